// Round 3
// baseline (278.419 us; speedup 1.0000x reference)
//
#include <hip/hip_runtime.h>

#define K      32
#define TPB    256
#define NB     1024                 // main-kernel blocks: 1024*256*8 = N
#define EPT    8                    // elements per thread (grid-stride)
#define NTOT   (32 * 64 * 1024)     // 2,097,152
#define STRIDE (TPB * NB)

__device__ __forceinline__ float wave_reduce_sum(float v) {
#pragma unroll
  for (int m = 1; m < 64; m <<= 1) v += __shfl_xor(v, m, 64);
  return v;
}

__device__ __forceinline__ float to_sgpr(float v) {
  return __int_as_float(__builtin_amdgcn_readfirstlane(__float_as_int(v)));
}

// (256,4): VGPR cap 128 -> 4 waves/SIMD, all 4096 waves co-resident.
// Live set ~90 VGPRs (t[32]+sAcc[32]+xs[8]+working) -- fits. R0's spill was a
// 64-reg cap against a ~130 live set; this is deliberate, not that.
__global__ __launch_bounds__(TPB, 4)
void ssq_main(const float* __restrict__ x, const float* __restrict__ bins,
              float* __restrict__ out, float* __restrict__ partials) {
  const int tid  = threadIdx.x;
  const int base = blockIdx.x * TPB + tid;

  // force bins into SGPRs (saves 32 VGPRs vs vector copies)
  float binv[K];
#pragma unroll
  for (int k = 0; k < K; ++k) binv[k] = to_sgpr(bins[k]);
  float binsum = 0.f;
#pragma unroll
  for (int k = 0; k < K; ++k) binsum += binv[k];
  const float epsb = 1e-10f * binsum;   // eps * sum(bins) term of bit_code

  float xs[EPT];
#pragma unroll
  for (int e = 0; e < EPT; ++e) xs[e] = x[base + e * STRIDE];

  float sAcc[K];
#pragma unroll
  for (int k = 0; k < K; ++k) sAcc[k] = 0.f;
  float q = 0.f;

  const float Ch = -7.213475204444817f;  // 0.5 * ALPHA * log2(e)

#pragma unroll
  for (int e = 0; e < EPT; ++e) {
    const float xv = xs[e];
    float t[K];
    float s0 = 0.f, s1 = 0.f, s2 = 0.f, s3 = 0.f;      // sum of t = h^2
    float h0 = 0.f, h1 = 0.f, h2 = 0.f, h3 = 0.f;      // sum of h = sqrt(t)
    float b0 = 0.f, b1 = 0.f, b2 = 0.f, b3 = 0.f;      // sum of t*bin
#pragma unroll
    for (int k = 0; k < K; k += 4) {
      float ha = __builtin_amdgcn_exp2f(Ch * fabsf(xv - binv[k + 0]));
      float hb = __builtin_amdgcn_exp2f(Ch * fabsf(xv - binv[k + 1]));
      float hc = __builtin_amdgcn_exp2f(Ch * fabsf(xv - binv[k + 2]));
      float hd = __builtin_amdgcn_exp2f(Ch * fabsf(xv - binv[k + 3]));
      float ta = ha * ha, tb = hb * hb, tc = hc * hc, td = hd * hd;
      t[k + 0] = ta; t[k + 1] = tb; t[k + 2] = tc; t[k + 3] = td;
      s0 += ta; s1 += tb; s2 += tc; s3 += td;
      h0 += ha; h1 += hb; h2 += hc; h3 += hd;
      b0 = fmaf(ta, binv[k + 0], b0);
      b1 = fmaf(tb, binv[k + 1], b1);
      b2 = fmaf(tc, binv[k + 2], b2);
      b3 = fmaf(td, binv[k + 3], b3);
    }
    const float s    = (s0 + s1) + (s2 + s3);
    const float hsum = (h0 + h1) + (h2 + h3);
    const float bnum = (b0 + b1) + (b2 + b3);
    const float inv  = __builtin_amdgcn_rcpf(s);
    const float rq   = __builtin_amdgcn_rsqf(s);
    q = fmaf(hsum, rq, q);                       // sum_k sqrt(a_k) = rsqrt(s)*sum h
    out[base + e * STRIDE] = fmaf(bnum, inv, epsb);
#pragma unroll
    for (int k = 0; k < K; ++k) sAcc[k] = fmaf(t[k], inv, sAcc[k]);
  }

  // block reduction: wave shuffle -> LDS -> one partial per counter per block
  __shared__ float red[4][K + 1];
  const int lane = tid & 63, wv = tid >> 6;
#pragma unroll
  for (int k = 0; k < K; ++k) {
    float v = wave_reduce_sum(sAcc[k]);
    if (lane == 0) red[wv][k] = v;
  }
  {
    float v = wave_reduce_sum(q);
    if (lane == 0) red[wv][K] = v;
  }
  __syncthreads();
  if (tid < K + 1) {
    float v = red[0][tid] + red[1][tid] + red[2][tid] + red[3][tid];
    partials[tid * NB + blockIdx.x] = v;   // written exactly once, no init needed
  }
}

// 33 blocks: block c reduces partials[c*NB .. c*NB+NB) -> sums[c]
__global__ __launch_bounds__(TPB)
void ssq_reduce(const float* __restrict__ partials, float* __restrict__ sums) {
  const float* p = partials + blockIdx.x * NB;
  const int tid  = threadIdx.x;
  float s = p[tid] + p[tid + 256] + p[tid + 512] + p[tid + 768];
  s = wave_reduce_sum(s);
  __shared__ float red[4];
  if ((tid & 63) == 0) red[tid >> 6] = s;
  __syncthreads();
  if (tid == 0) sums[blockIdx.x] = red[0] + red[1] + red[2] + red[3];
}

// one wave: entropy over 32 p_k + quant mean + tails
__global__ void ssq_final(const float* __restrict__ sums, float* __restrict__ out) {
  const int lane = threadIdx.x;
  float e = 0.f;
  if (lane < K) {
    float p = sums[lane] * (1.0f / (float)NTOT) + 1e-10f;  // eps folded in here
    e = -p * __logf(p);
  }
  e = wave_reduce_sum(e);
  if (lane == 0) {
    out[NTOT + 0] = e;                              // code entropy
    out[NTOT + 1] = 0.f;                            // TAU
    out[NTOT + 2] = sums[K] * (1.0f / (float)NTOT); // quant loss
    out[NTOT + 3] = 0.f;                            // TAU2
  }
}

extern "C" void kernel_launch(void* const* d_in, const int* in_sizes, int n_in,
                              void* d_out, int out_size, void* d_ws, size_t ws_size,
                              hipStream_t stream) {
  const float* x    = (const float*)d_in[0];
  const float* bins = (const float*)d_in[1];
  float* out        = (float*)d_out;
  float* partials   = (float*)d_ws;                 // (K+1)*NB floats = 132 KB
  float* sums       = partials + (K + 1) * NB;      // 33 floats

  ssq_main  <<<NB,    TPB, 0, stream>>>(x, bins, out, partials);
  ssq_reduce<<<K + 1, TPB, 0, stream>>>(partials, sums);
  ssq_final <<<1,     64,  0, stream>>>(sums, out);
}

// Round 4
// 139.876 us; speedup vs baseline: 1.9905x; 1.9905x over previous
//
#include <hip/hip_runtime.h>

#define K      32
#define TPB    256
#define NB     1024                 // main-kernel blocks: 1024*256*8 = N
#define EPT    8                    // elements per thread (grid-stride)
#define NTOT   (32 * 64 * 1024)     // 2,097,152
#define STRIDE (TPB * NB)

__device__ __forceinline__ float wave_reduce_sum(float v) {
#pragma unroll
  for (int m = 1; m < 64; m <<= 1) v += __shfl_xor(v, m, 64);
  return v;
}

__device__ __forceinline__ float to_sgpr(float v) {
  return __int_as_float(__builtin_amdgcn_readfirstlane(__float_as_int(v)));
}

// NO 2nd launch_bounds arg: R2's (256,4) made the compiler allocate 64 VGPRs
// -> 166/333 MB spill traffic. Occupancy comes from the structural register
// diet below (two-pass, no t[32]/sAcc[32] arrays), not from allocator caps.
__global__ __launch_bounds__(TPB)
void ssq_main(const float* __restrict__ x, const float* __restrict__ bins,
              float* __restrict__ out, float* __restrict__ partials) {
  const int tid  = threadIdx.x;
  const int base = blockIdx.x * TPB + tid;

  // wave-uniform -> SGPRs
  float binv[K];
#pragma unroll
  for (int k = 0; k < K; ++k) binv[k] = to_sgpr(bins[k]);
  float binsum = 0.f;
#pragma unroll
  for (int k = 0; k < K; ++k) binsum += binv[k];
  const float epsb = 1e-10f * binsum;    // eps * sum(bins) term of bit_code

  float xs[EPT];
#pragma unroll
  for (int e = 0; e < EPT; ++e) xs[e] = x[base + e * STRIDE];

  const float Ch = -7.213475204444817f;   // 0.5 * ALPHA * log2(e)
  const float Cf = -14.426950408889634f;  // ALPHA * log2(e)

  // ---- pass 1: per-element softmax denominator s, sqrt-sum hs, numerator b
  float sv[EPT], hs[EPT], bn[EPT];
#pragma unroll
  for (int e = 0; e < EPT; ++e) {
    const float xv = xs[e];
    float s0 = 0.f, s1 = 0.f, h0 = 0.f, h1 = 0.f, b0 = 0.f, b1 = 0.f;
#pragma unroll
    for (int k = 0; k < K; k += 2) {
      float ha = __builtin_amdgcn_exp2f(Ch * fabsf(xv - binv[k + 0]));
      float hb = __builtin_amdgcn_exp2f(Ch * fabsf(xv - binv[k + 1]));
      float ta = ha * ha, tb = hb * hb;
      s0 += ta; s1 += tb;
      h0 += ha; h1 += hb;
      b0 = fmaf(ta, binv[k + 0], b0);
      b1 = fmaf(tb, binv[k + 1], b1);
    }
    sv[e] = s0 + s1; hs[e] = h0 + h1; bn[e] = b0 + b1;
  }

  // ---- interlude: reciprocals, quant partial, bit_code stores
  float inv[EPT];
  float q = 0.f;
#pragma unroll
  for (int e = 0; e < EPT; ++e) {
    inv[e] = __builtin_amdgcn_rcpf(sv[e]);
    q = fmaf(hs[e], __builtin_amdgcn_rsqf(sv[e]), q);  // sum_k sqrt(a) = rsqrt(s)*sum h
    out[base + e * STRIDE] = fmaf(bn[e], inv[e], epsb);
  }

  // ---- pass 2: per-bin assignment sums; k-outer so no sAcc[32] array lives.
  // Each wave reduces its 512 element-contributions for bin k immediately.
  __shared__ float red[4][K + 1];
  const int lane = tid & 63, wv = tid >> 6;
#pragma unroll
  for (int k = 0; k < K; ++k) {
    const float bk = binv[k];
    float a0 = 0.f, a1 = 0.f;
#pragma unroll
    for (int e = 0; e < EPT; e += 2) {
      a0 = fmaf(__builtin_amdgcn_exp2f(Cf * fabsf(xs[e + 0] - bk)), inv[e + 0], a0);
      a1 = fmaf(__builtin_amdgcn_exp2f(Cf * fabsf(xs[e + 1] - bk)), inv[e + 1], a1);
    }
    float v = wave_reduce_sum(a0 + a1);
    if (lane == 0) red[wv][k] = v;
  }
  {
    float v = wave_reduce_sum(q);
    if (lane == 0) red[wv][K] = v;
  }
  __syncthreads();
  if (tid < K + 1) {
    float v = red[0][tid] + red[1][tid] + red[2][tid] + red[3][tid];
    partials[tid * NB + blockIdx.x] = v;   // written exactly once, no init needed
  }
}

// 33 blocks: block c reduces partials[c*NB .. c*NB+NB) -> sums[c]
__global__ __launch_bounds__(TPB)
void ssq_reduce(const float* __restrict__ partials, float* __restrict__ sums) {
  const float* p = partials + blockIdx.x * NB;
  const int tid  = threadIdx.x;
  float s = p[tid] + p[tid + 256] + p[tid + 512] + p[tid + 768];
  s = wave_reduce_sum(s);
  __shared__ float red[4];
  if ((tid & 63) == 0) red[tid >> 6] = s;
  __syncthreads();
  if (tid == 0) sums[blockIdx.x] = red[0] + red[1] + red[2] + red[3];
}

// one wave: entropy over 32 p_k + quant mean + tails
__global__ void ssq_final(const float* __restrict__ sums, float* __restrict__ out) {
  const int lane = threadIdx.x;
  float e = 0.f;
  if (lane < K) {
    float p = sums[lane] * (1.0f / (float)NTOT) + 1e-10f;  // eps folded in here
    e = -p * __logf(p);
  }
  e = wave_reduce_sum(e);
  if (lane == 0) {
    out[NTOT + 0] = e;                              // code entropy
    out[NTOT + 1] = 0.f;                            // TAU
    out[NTOT + 2] = sums[K] * (1.0f / (float)NTOT); // quant loss
    out[NTOT + 3] = 0.f;                            // TAU2
  }
}

extern "C" void kernel_launch(void* const* d_in, const int* in_sizes, int n_in,
                              void* d_out, int out_size, void* d_ws, size_t ws_size,
                              hipStream_t stream) {
  const float* x    = (const float*)d_in[0];
  const float* bins = (const float*)d_in[1];
  float* out        = (float*)d_out;
  float* partials   = (float*)d_ws;                 // (K+1)*NB floats = 132 KB
  float* sums       = partials + (K + 1) * NB;      // 33 floats

  ssq_main  <<<NB,    TPB, 0, stream>>>(x, bins, out, partials);
  ssq_reduce<<<K + 1, TPB, 0, stream>>>(partials, sums);
  ssq_final <<<1,     64,  0, stream>>>(sums, out);
}

// Round 5
// 87.241 us; speedup vs baseline: 3.1914x; 1.6033x over previous
//
#include <hip/hip_runtime.h>

#define K      32
#define TPB    256
#define NB     2048                 // main-kernel blocks: 2048*256*4 = N
#define EPT    4                    // elements per thread (grid-stride)
#define NTOT   (32 * 64 * 1024)     // 2,097,152
#define STRIDE (TPB * NB)           // 524288

__device__ __forceinline__ float wave_reduce_sum(float v) {
#pragma unroll
  for (int m = 1; m < 64; m <<= 1) v += __shfl_xor(v, m, 64);
  return v;
}

__device__ __forceinline__ float to_sgpr(float v) {
  return __int_as_float(__builtin_amdgcn_readfirstlane(__float_as_int(v)));
}

// Register-pressure control is STRUCTURAL, learned the hard way:
//  - R0/R2: launch_bounds caps -> allocator spills (250/166 MB traffic). Never cap.
//  - R4(prev): full unroll of e-loop -> allocator pipelines across elements,
//    256 VGPRs, 2 waves/SIMD. Fix: '#pragma unroll 1' on the e-loop so t[32]
//    provably dies each iteration. Target ~100 VGPRs -> 5 waves/SIMD.
__global__ __launch_bounds__(TPB)
void ssq_main(const float* __restrict__ x, const float* __restrict__ bins,
              float* __restrict__ out, float* __restrict__ partials) {
  const int tid  = threadIdx.x;
  const int base = blockIdx.x * TPB + tid;

  // wave-uniform -> SGPRs
  float binv[K];
#pragma unroll
  for (int k = 0; k < K; ++k) binv[k] = to_sgpr(bins[k]);
  float binsum = 0.f;
#pragma unroll
  for (int k = 0; k < K; ++k) binsum += binv[k];
  const float epsb = 1e-10f * binsum;    // eps * sum(bins) term of bit_code

  float xs[EPT];
#pragma unroll
  for (int e = 0; e < EPT; ++e) xs[e] = x[base + e * STRIDE];

  float sAcc[K];
#pragma unroll
  for (int k = 0; k < K; ++k) sAcc[k] = 0.f;
  float q = 0.f;

  const float Ch = -7.213475204444817f;   // 0.5 * ALPHA * log2(e)

#pragma unroll 1
  for (int e = 0; e < EPT; ++e) {
    const float xv = xs[e];
    float t[K];                           // lives only inside this iteration
    float s0 = 0.f, s1 = 0.f, h0 = 0.f, h1 = 0.f, b0 = 0.f, b1 = 0.f;
#pragma unroll
    for (int k = 0; k < K; k += 2) {
      float ha = __builtin_amdgcn_exp2f(Ch * fabsf(xv - binv[k + 0]));
      float hb = __builtin_amdgcn_exp2f(Ch * fabsf(xv - binv[k + 1]));
      float ta = ha * ha, tb = hb * hb;
      t[k + 0] = ta; t[k + 1] = tb;
      s0 += ta; s1 += tb;
      h0 += ha; h1 += hb;
      b0 = fmaf(ta, binv[k + 0], b0);
      b1 = fmaf(tb, binv[k + 1], b1);
    }
    const float s    = s0 + s1;
    const float inv  = __builtin_amdgcn_rcpf(s);
    q = fmaf(h0 + h1, __builtin_amdgcn_rsqf(s), q);  // sum_k sqrt(a) = rsqrt(s)*sum h
    out[base + e * STRIDE] = fmaf(b0 + b1, inv, epsb);
#pragma unroll
    for (int k = 0; k < K; ++k) sAcc[k] = fmaf(t[k], inv, sAcc[k]);
  }

  // block reduction: wave shuffle -> LDS -> one partial per counter per block
  __shared__ float red[4][K + 1];
  const int lane = tid & 63, wv = tid >> 6;
#pragma unroll
  for (int k = 0; k < K; ++k) {
    float v = wave_reduce_sum(sAcc[k]);
    if (lane == 0) red[wv][k] = v;
  }
  {
    float v = wave_reduce_sum(q);
    if (lane == 0) red[wv][K] = v;
  }
  __syncthreads();
  if (tid < K + 1) {
    float v = red[0][tid] + red[1][tid] + red[2][tid] + red[3][tid];
    partials[tid * NB + blockIdx.x] = v;   // written exactly once, no init needed
  }
}

// 33 blocks: block c reduces partials[c*NB .. c*NB+NB) -> sums[c]
__global__ __launch_bounds__(TPB)
void ssq_reduce(const float* __restrict__ partials, float* __restrict__ sums) {
  const float* p = partials + blockIdx.x * NB;
  const int tid  = threadIdx.x;
  float s = 0.f;
#pragma unroll
  for (int j = 0; j < NB / TPB; ++j) s += p[tid + j * TPB];
  s = wave_reduce_sum(s);
  __shared__ float red[4];
  if ((tid & 63) == 0) red[tid >> 6] = s;
  __syncthreads();
  if (tid == 0) sums[blockIdx.x] = red[0] + red[1] + red[2] + red[3];
}

// one wave: entropy over 32 p_k + quant mean + tails
__global__ void ssq_final(const float* __restrict__ sums, float* __restrict__ out) {
  const int lane = threadIdx.x;
  float e = 0.f;
  if (lane < K) {
    float p = sums[lane] * (1.0f / (float)NTOT) + 1e-10f;  // eps folded in here
    e = -p * __logf(p);
  }
  e = wave_reduce_sum(e);
  if (lane == 0) {
    out[NTOT + 0] = e;                              // code entropy
    out[NTOT + 1] = 0.f;                            // TAU
    out[NTOT + 2] = sums[K] * (1.0f / (float)NTOT); // quant loss
    out[NTOT + 3] = 0.f;                            // TAU2
  }
}

extern "C" void kernel_launch(void* const* d_in, const int* in_sizes, int n_in,
                              void* d_out, int out_size, void* d_ws, size_t ws_size,
                              hipStream_t stream) {
  const float* x    = (const float*)d_in[0];
  const float* bins = (const float*)d_in[1];
  float* out        = (float*)d_out;
  float* partials   = (float*)d_ws;                 // (K+1)*NB floats = 264 KB
  float* sums       = partials + (K + 1) * NB;      // 33 floats

  ssq_main  <<<NB,    TPB, 0, stream>>>(x, bins, out, partials);
  ssq_reduce<<<K + 1, TPB, 0, stream>>>(partials, sums);
  ssq_final <<<1,     64,  0, stream>>>(sums, out);
}